// Round 1
// baseline (555.281 us; speedup 1.0000x reference)
//
#include <hip/hip_runtime.h>
#include <math.h>

#define N_PTS 131072
#define BSEG 64
#define C 256
#define CH 16           // chunks per segment for partial softmax reduce

#define BM 128
#define BN 64
#define BK 32
#define LDA (BM + 4)    // 132 floats -> 528B rows, 16B aligned
#define LDB (BN + 4)    // 68 floats  -> 272B rows, 16B aligned

#define INV_SQRT_DH 0.17677669529663687f  // 1/sqrt(32)

// ---------------------------------------------------------------------------
// K0: segment boundaries via binary search over sorted batch ids
// ---------------------------------------------------------------------------
__global__ void seg_bounds_kernel(const int* __restrict__ batch,
                                  int* __restrict__ seg, int n) {
    int b = threadIdx.x;
    if (b < BSEG) {
        int lo = 0, hi = n;
        while (lo < hi) {
            int mid = (lo + hi) >> 1;
            if (batch[mid] < b) lo = mid + 1; else hi = mid;
        }
        seg[b] = lo;
    }
    if (threadIdx.x == 0) seg[BSEG] = n;
}

// ---------------------------------------------------------------------------
// K1: kp = k @ Wk^T + bk ; vp = v @ Wv^T + bv   (tiny: 64x256, K=256)
// ---------------------------------------------------------------------------
__global__ __launch_bounds__(256) void kv_proj_kernel(
    const float* __restrict__ k, const float* __restrict__ v,
    const float* __restrict__ Wk, const float* __restrict__ bk,
    const float* __restrict__ Wv, const float* __restrict__ bv,
    float* __restrict__ kp, float* __restrict__ vp) {
    int b = blockIdx.x;    // 0..63
    int c = threadIdx.x;   // 0..255
    const float4* krow  = (const float4*)(k + (size_t)b * C);
    const float4* vrow  = (const float4*)(v + (size_t)b * C);
    const float4* wkrow = (const float4*)(Wk + (size_t)c * C);
    const float4* wvrow = (const float4*)(Wv + (size_t)c * C);
    float accK = 0.f, accV = 0.f;
    #pragma unroll 8
    for (int i = 0; i < C / 4; ++i) {
        float4 kk = krow[i], wk = wkrow[i];
        accK += kk.x * wk.x + kk.y * wk.y + kk.z * wk.z + kk.w * wk.w;
        float4 vv = vrow[i], wv = wvrow[i];
        accV += vv.x * wv.x + vv.y * wv.y + vv.z * wv.z + vv.w * wv.w;
    }
    kp[b * C + c] = accK + bk[c];
    vp[b * C + c] = accV + bv[c];
}

// ---------------------------------------------------------------------------
// K2/K5: tiled fp32 GEMM  Out = A @ W^T (+bias, optional attn epilogue)
//   A: [M,256] row-major, W: [256,256] row-major (rows = output cols)
//   EPI==1: Out[n,c] = (acc + bias[c]) * kp[batch[n],c] * (1/sqrt(32))
//   EPI==0: Out[n,c] =  acc + bias[c]
// ---------------------------------------------------------------------------
template <int EPI>
__global__ __launch_bounds__(256) void gemm_nt_kernel(
    const float* __restrict__ A, const float* __restrict__ W,
    const float* __restrict__ bias, float* __restrict__ Out,
    const int* __restrict__ batch, const float* __restrict__ kp) {
    __shared__ float As[BK][LDA];
    __shared__ float Bs[BK][LDB];

    const int tid = threadIdx.x;
    const int tx = tid & 15;   // col group: 16 -> 64 cols (4 each)
    const int ty = tid >> 4;   // row group: 16 -> 128 rows (8 each)
    const int m0 = blockIdx.y * BM;
    const int n0 = blockIdx.x * BN;

    float acc[8][4];
    #pragma unroll
    for (int i = 0; i < 8; ++i)
        #pragma unroll
        for (int j = 0; j < 4; ++j) acc[i][j] = 0.f;

    for (int kt = 0; kt < 256; kt += BK) {
        // A tile: 128 rows x 32 k -> 1024 float4, 4 per thread, coalesced
        #pragma unroll
        for (int i = 0; i < 4; ++i) {
            int j = tid + i * 256;
            int row = j >> 3;
            int kk4 = j & 7;
            float4 a = *(const float4*)(A + (size_t)(m0 + row) * C + kt + kk4 * 4);
            As[kk4 * 4 + 0][row] = a.x;
            As[kk4 * 4 + 1][row] = a.y;
            As[kk4 * 4 + 2][row] = a.z;
            As[kk4 * 4 + 3][row] = a.w;
        }
        // B tile: 64 n-rows x 32 k -> 512 float4, 2 per thread
        #pragma unroll
        for (int i = 0; i < 2; ++i) {
            int j = tid + i * 256;
            int nrow = j >> 3;
            int kk4 = j & 7;
            float4 w4 = *(const float4*)(W + (size_t)(n0 + nrow) * C + kt + kk4 * 4);
            Bs[kk4 * 4 + 0][nrow] = w4.x;
            Bs[kk4 * 4 + 1][nrow] = w4.y;
            Bs[kk4 * 4 + 2][nrow] = w4.z;
            Bs[kk4 * 4 + 3][nrow] = w4.w;
        }
        __syncthreads();
        #pragma unroll
        for (int kk = 0; kk < BK; ++kk) {
            float4 a0 = *(const float4*)&As[kk][ty * 8];
            float4 a1 = *(const float4*)&As[kk][ty * 8 + 4];
            float4 b4 = *(const float4*)&Bs[kk][tx * 4];
            float av[8] = {a0.x, a0.y, a0.z, a0.w, a1.x, a1.y, a1.z, a1.w};
            float bw[4] = {b4.x, b4.y, b4.z, b4.w};
            #pragma unroll
            for (int i = 0; i < 8; ++i)
                #pragma unroll
                for (int j = 0; j < 4; ++j) acc[i][j] += av[i] * bw[j];
        }
        __syncthreads();
    }

    const int col0 = n0 + tx * 4;
    float4 bb = *(const float4*)(bias + col0);
    #pragma unroll
    for (int i = 0; i < 8; ++i) {
        int row = m0 + ty * 8 + i;
        float4 o;
        o.x = acc[i][0] + bb.x;
        o.y = acc[i][1] + bb.y;
        o.z = acc[i][2] + bb.z;
        o.w = acc[i][3] + bb.w;
        if (EPI == 1) {
            int b = batch[row];
            float4 kk = *(const float4*)(kp + (size_t)b * C + col0);
            o.x *= kk.x * INV_SQRT_DH;
            o.y *= kk.y * INV_SQRT_DH;
            o.z *= kk.z * INV_SQRT_DH;
            o.w *= kk.w * INV_SQRT_DH;
        }
        *(float4*)(Out + (size_t)row * C + col0) = o;
    }
}

// ---------------------------------------------------------------------------
// K3a: per-(segment,chunk,channel) online max+sum partials
// ---------------------------------------------------------------------------
__global__ __launch_bounds__(256) void seg_stats_partial(
    const float* __restrict__ attn, const int* __restrict__ seg,
    float* __restrict__ pm, float* __restrict__ ps) {
    int b = blockIdx.x;    // segment
    int ch = blockIdx.y;   // chunk
    int c = threadIdx.x;   // channel
    int s = seg[b], e = seg[b + 1];
    int len = e - s;
    int i0 = s + (int)((long long)len * ch / CH);
    int i1 = s + (int)((long long)len * (ch + 1) / CH);
    float m = -1e30f, sum = 0.f;
    for (int n = i0; n < i1; ++n) {
        float x = attn[(size_t)n * C + c];
        float mn = fmaxf(m, x);
        sum = sum * __expf(m - mn) + __expf(x - mn);
        m = mn;
    }
    int idx = (b * CH + ch) * C + c;
    pm[idx] = m;
    ps[idx] = sum;
}

// ---------------------------------------------------------------------------
// K3b: combine chunk partials -> m[b,c], 1/s[b,c]
// ---------------------------------------------------------------------------
__global__ __launch_bounds__(256) void seg_stats_combine(
    const float* __restrict__ pm, const float* __restrict__ ps,
    float* __restrict__ mbuf, float* __restrict__ srcp) {
    int b = blockIdx.x;
    int c = threadIdx.x;
    float m = -1e30f;
    #pragma unroll
    for (int ch = 0; ch < CH; ++ch) m = fmaxf(m, pm[(b * CH + ch) * C + c]);
    float s = 0.f;
    #pragma unroll
    for (int ch = 0; ch < CH; ++ch)
        s += ps[(b * CH + ch) * C + c] * __expf(pm[(b * CH + ch) * C + c] - m);
    mbuf[b * C + c] = m;
    srcp[b * C + c] = 1.0f / s;   // inf only for empty segments (never read)
}

// ---------------------------------------------------------------------------
// K4: in-place  attn[n,c] = exp(attn - m[b,c]) * (1/s[b,c]) * vp[b,c]
// ---------------------------------------------------------------------------
__global__ __launch_bounds__(256) void apply_softmax_v(
    float* __restrict__ attn, const int* __restrict__ batch,
    const float* __restrict__ mbuf, const float* __restrict__ srcp,
    const float* __restrict__ vp) {
    const size_t total = (size_t)N_PTS * C / 4;
    for (size_t i4 = (size_t)blockIdx.x * blockDim.x + threadIdx.x; i4 < total;
         i4 += (size_t)gridDim.x * blockDim.x) {
        int n = (int)(i4 >> 6);          // 64 float4 per row
        int c0 = ((int)i4 & 63) * 4;
        int b = batch[n];
        float4 x = ((float4*)attn)[i4];
        const float* mb = mbuf + b * C + c0;
        const float* sb = srcp + b * C + c0;
        const float* vb = vp + b * C + c0;
        float4 o;
        o.x = __expf(x.x - mb[0]) * sb[0] * vb[0];
        o.y = __expf(x.y - mb[1]) * sb[1] * vb[1];
        o.z = __expf(x.z - mb[2]) * sb[2] * vb[2];
        o.w = __expf(x.w - mb[3]) * sb[3] * vb[3];
        ((float4*)attn)[i4] = o;
    }
}

// ---------------------------------------------------------------------------
extern "C" void kernel_launch(void* const* d_in, const int* in_sizes, int n_in,
                              void* d_out, int out_size, void* d_ws, size_t ws_size,
                              hipStream_t stream) {
    const float* q  = (const float*)d_in[0];
    const float* k  = (const float*)d_in[1];
    const float* v  = (const float*)d_in[2];
    const int* batch = (const int*)d_in[3];
    const float* Wq = (const float*)d_in[4];
    const float* bq = (const float*)d_in[5];
    const float* Wk = (const float*)d_in[6];
    const float* bk = (const float*)d_in[7];
    const float* Wv = (const float*)d_in[8];
    const float* bv = (const float*)d_in[9];
    const float* Wo = (const float*)d_in[10];
    const float* bo = (const float*)d_in[11];
    float* out = (float*)d_out;

    char* w = (char*)d_ws;
    float* attn = (float*)w;  w += (size_t)N_PTS * C * sizeof(float);
    float* kp   = (float*)w;  w += (size_t)BSEG * C * sizeof(float);
    float* vp   = (float*)w;  w += (size_t)BSEG * C * sizeof(float);
    float* mbuf = (float*)w;  w += (size_t)BSEG * C * sizeof(float);
    float* srcp = (float*)w;  w += (size_t)BSEG * C * sizeof(float);
    float* pm   = (float*)w;  w += (size_t)BSEG * CH * C * sizeof(float);
    float* ps   = (float*)w;  w += (size_t)BSEG * CH * C * sizeof(float);
    int*   seg  = (int*)w;    w += (BSEG + 1) * sizeof(int);

    seg_bounds_kernel<<<1, 64, 0, stream>>>(batch, seg, N_PTS);
    kv_proj_kernel<<<BSEG, 256, 0, stream>>>(k, v, Wk, bk, Wv, bv, kp, vp);
    gemm_nt_kernel<1><<<dim3(C / BN, N_PTS / BM), 256, 0, stream>>>(
        q, Wq, bq, attn, batch, kp);
    seg_stats_partial<<<dim3(BSEG, CH), 256, 0, stream>>>(attn, seg, pm, ps);
    seg_stats_combine<<<BSEG, 256, 0, stream>>>(pm, ps, mbuf, srcp);
    apply_softmax_v<<<4096, 256, 0, stream>>>(attn, batch, mbuf, srcp, vp);
    gemm_nt_kernel<0><<<dim3(C / BN, N_PTS / BM), 256, 0, stream>>>(
        attn, Wo, bo, out, nullptr, nullptr);
}

// Round 3
// 259.046 us; speedup vs baseline: 2.1436x; 2.1436x over previous
//
#include <hip/hip_runtime.h>
#include <math.h>

#define N_PTS 131072
#define BSEG 64
#define CC 256
#define CH 16

#define BM 128
#define BN 128
#define BK 32
#define NSTEP (CC / BK)          // 8 K-steps
#define LDS_BUF 16384            // shorts per buffer: A 8192 + B 8192 (32KB)

#define INV_SQRT_DH 0.17677669529663687f  // 1/sqrt(32)

typedef short v8s __attribute__((ext_vector_type(8)));
typedef float v4f __attribute__((ext_vector_type(4)));

__device__ __forceinline__ float bf2f(unsigned short h) {
    unsigned u = ((unsigned)h) << 16;
    return __builtin_bit_cast(float, u);
}

// f32 -> bf16 with round-to-nearest-even (no NaN special-casing needed here)
__device__ __forceinline__ unsigned short f2bf(float f) {
    unsigned u = __builtin_bit_cast(unsigned, f);
    u += 0x7fffu + ((u >> 16) & 1u);
    return (unsigned short)(u >> 16);
}

// split 8 fp32 -> 8 bf16 hi (RNE) + 8 bf16 lo (RNE of residual), packed 4+4 ints
__device__ __forceinline__ void split8(const float* x, int* hi2, int* lo2) {
    #pragma unroll
    for (int i = 0; i < 4; ++i) {
        float a = x[2 * i], b = x[2 * i + 1];
        unsigned short ha = f2bf(a), hb = f2bf(b);
        float ra = a - bf2f(ha), rb = b - bf2f(hb);
        unsigned short la = f2bf(ra), lb = f2bf(rb);
        hi2[i] = (int)(((unsigned)hb << 16) | ha);
        lo2[i] = (int)(((unsigned)lb << 16) | la);
    }
}

__device__ __forceinline__ v8s as_v8s(int4 v) { return __builtin_bit_cast(v8s, v); }

// ---------------------------------------------------------------------------
// K0: segment boundaries via binary search over sorted batch ids
// ---------------------------------------------------------------------------
__global__ void seg_bounds_kernel(const int* __restrict__ batch,
                                  int* __restrict__ seg, int n) {
    int b = threadIdx.x;
    if (b < BSEG) {
        int lo = 0, hi = n;
        while (lo < hi) {
            int mid = (lo + hi) >> 1;
            if (batch[mid] < b) lo = mid + 1; else hi = mid;
        }
        seg[b] = lo;
    }
    if (threadIdx.x == 0) seg[BSEG] = n;
}

// ---------------------------------------------------------------------------
// K1: kps = (k @ Wk^T + bk) * 1/sqrt(DH) ; vp = v @ Wv^T + bv
// ---------------------------------------------------------------------------
__global__ __launch_bounds__(256) void kv_proj_kernel(
    const float* __restrict__ k, const float* __restrict__ v,
    const float* __restrict__ Wk, const float* __restrict__ bk,
    const float* __restrict__ Wv, const float* __restrict__ bv,
    float* __restrict__ kps, float* __restrict__ vp) {
    int b = blockIdx.x;
    int c = threadIdx.x;
    const float4* krow  = (const float4*)(k + (size_t)b * CC);
    const float4* vrow  = (const float4*)(v + (size_t)b * CC);
    const float4* wkrow = (const float4*)(Wk + (size_t)c * CC);
    const float4* wvrow = (const float4*)(Wv + (size_t)c * CC);
    float accK = 0.f, accV = 0.f;
    #pragma unroll 8
    for (int i = 0; i < CC / 4; ++i) {
        float4 kk = krow[i], wk = wkrow[i];
        accK += kk.x * wk.x + kk.y * wk.y + kk.z * wk.z + kk.w * wk.w;
        float4 vv = vrow[i], wv = wvrow[i];
        accV += vv.x * wv.x + vv.y * wv.y + vv.z * wv.z + vv.w * wv.w;
    }
    kps[b * CC + c] = (accK + bk[c]) * INV_SQRT_DH;
    vp[b * CC + c] = accV + bv[c];
}

// ---------------------------------------------------------------------------
// K1b: split Wq/Wo into hi/lo bf16 planes, k-fragment-major layout:
//   W2[plane p][kfrag kf (32)][n (256)][8 bf16]
// ---------------------------------------------------------------------------
__global__ __launch_bounds__(256) void wsplit_kernel(
    const float* __restrict__ Wq, const float* __restrict__ Wo,
    short* __restrict__ W2q, short* __restrict__ W2o) {
    int bx = blockIdx.x;                 // 0..63: mat = bx>>5, kf = bx&31
    const float* W = (bx >= 32) ? Wo : Wq;
    short* W2 = (bx >= 32) ? W2o : W2q;
    int kf = bx & 31;
    int n = threadIdx.x;
    const float* src = W + (size_t)n * CC + kf * 8;
    float x[8];
    float4 x0 = *(const float4*)(src);
    float4 x1 = *(const float4*)(src + 4);
    x[0]=x0.x; x[1]=x0.y; x[2]=x0.z; x[3]=x0.w;
    x[4]=x1.x; x[5]=x1.y; x[6]=x1.z; x[7]=x1.w;
    int hi2[4], lo2[4];
    split8(x, hi2, lo2);
    *(int4*)&W2[((size_t)(0 * 32 + kf) * 256 + n) * 8] = make_int4(hi2[0], hi2[1], hi2[2], hi2[3]);
    *(int4*)&W2[((size_t)(1 * 32 + kf) * 256 + n) * 8] = make_int4(lo2[0], lo2[1], lo2[2], lo2[3]);
}

// ---------------------------------------------------------------------------
// GEMM (bf16x3 MFMA):  Out[M,256] = A[M,256] @ W^T  (+ epilogue)
//  MODE 0: A = q (plain fp32), epilogue: (acc + bq[c]) * kps[batch[m], c] -> attn
//  MODE 1: A = attn with fused softmax staging w = exp(x - M[b,c]) * SV[b,c],
//          epilogue: acc + bo[c] -> out
// ---------------------------------------------------------------------------
template <int MODE>
__global__ __launch_bounds__(256) void gemm3_kernel(
    const float* __restrict__ A, const short* __restrict__ W2,
    const float* __restrict__ bias, float* __restrict__ Out,
    const int* __restrict__ batch, const float* __restrict__ kps,
    const float* __restrict__ M, const float* __restrict__ SV) {
    __shared__ short lds[2 * LDS_BUF];   // 64 KB

    const int tid = threadIdx.x;
    const int lane = tid & 63;
    const int w = tid >> 6;

    // XCD-chunked bijective swizzle (2048 blocks = 8 XCD * 256)
    int bid = blockIdx.x;
    int t = (bid & 7) * 256 + (bid >> 3);
    const int tm = t >> 1, tn = t & 1;
    const int m0 = tm * BM, n0 = tn * BN;

    const int wm = w >> 1, wn = w & 1;
    const int kfl = lane >> 4;      // fragment k-group 0..3
    const int rl = lane & 15;       // fragment row/col

    v4f acc[4][4];
    #pragma unroll
    for (int i = 0; i < 4; ++i)
        #pragma unroll
        for (int j = 0; j < 4; ++j) acc[i][j] = (v4f){0.f, 0.f, 0.f, 0.f};

    // ---- staging helpers ----
    auto stageA = [&](int buf, int s) {
        #pragma unroll
        for (int uu = 0; uu < 2; ++uu) {
            int id = tid * 2 + uu;          // 0..511
            int m = id >> 2, kf = id & 3;   // frag-row (m, kf)
            const float* src = A + (size_t)(m0 + m) * CC + s * BK + kf * 8;
            float4 x0 = *(const float4*)(src);
            float4 x1 = *(const float4*)(src + 4);
            float x[8];
            x[0]=x0.x; x[1]=x0.y; x[2]=x0.z; x[3]=x0.w;
            x[4]=x1.x; x[5]=x1.y; x[6]=x1.z; x[7]=x1.w;
            if (MODE == 1) {
                int b = batch[m0 + m];
                const float* mp = M + (size_t)b * CC + s * BK + kf * 8;
                const float* sp = SV + (size_t)b * CC + s * BK + kf * 8;
                float4 m0v = *(const float4*)(mp);
                float4 m1v = *(const float4*)(mp + 4);
                float4 s0v = *(const float4*)(sp);
                float4 s1v = *(const float4*)(sp + 4);
                x[0] = __expf(x[0] - m0v.x) * s0v.x;
                x[1] = __expf(x[1] - m0v.y) * s0v.y;
                x[2] = __expf(x[2] - m0v.z) * s0v.z;
                x[3] = __expf(x[3] - m0v.w) * s0v.w;
                x[4] = __expf(x[4] - m1v.x) * s1v.x;
                x[5] = __expf(x[5] - m1v.y) * s1v.y;
                x[6] = __expf(x[6] - m1v.z) * s1v.z;
                x[7] = __expf(x[7] - m1v.w) * s1v.w;
            }
            int hi2[4], lo2[4];
            split8(x, hi2, lo2);
            int slot = kf * 128 + m;                    // [kf][m]
            *(int4*)&lds[buf * LDS_BUF + (size_t)slot * 8] =
                make_int4(hi2[0], hi2[1], hi2[2], hi2[3]);
            *(int4*)&lds[buf * LDS_BUF + (size_t)(512 + slot) * 8] =
                make_int4(lo2[0], lo2[1], lo2[2], lo2[3]);
        }
    };
    auto stageB = [&](int buf, int s) {
        #pragma unroll
        for (int j = 0; j < 4; ++j) {
            int id = w * 4 + j;                 // 0..15
            int p = id >> 3, kf = (id >> 1) & 3, h = id & 1;
            const short* g = W2 + ((size_t)(p * 32 + s * 4 + kf) * 256 + n0 + h * 64 + lane) * 8;
            short* l = &lds[buf * LDS_BUF + 8192 + (size_t)((p * 4 + kf) * 128 + h * 64) * 8];
            __builtin_amdgcn_global_load_lds(
                (const __attribute__((address_space(1))) void*)g,
                (__attribute__((address_space(3))) void*)l, 16, 0, 0);
        }
    };

    stageA(0, 0);
    stageB(0, 0);
    __syncthreads();

    int buf = 0;
    for (int s = 0; s < NSTEP; ++s) {
        if (s + 1 < NSTEP) { stageA(buf ^ 1, s + 1); stageB(buf ^ 1, s + 1); }

        v8s af[2][4], bfr[2][4];
        #pragma unroll
        for (int p = 0; p < 2; ++p)
            #pragma unroll
            for (int mi = 0; mi < 4; ++mi)
                af[p][mi] = as_v8s(*(const int4*)&lds[buf * LDS_BUF +
                    (size_t)(p * 512 + kfl * 128 + wm * 64 + mi * 16 + rl) * 8]);
        #pragma unroll
        for (int p = 0; p < 2; ++p)
            #pragma unroll
            for (int ni = 0; ni < 4; ++ni)
                bfr[p][ni] = as_v8s(*(const int4*)&lds[buf * LDS_BUF + 8192 +
                    (size_t)(p * 512 + kfl * 128 + wn * 64 + ni * 16 + rl) * 8]);

        #pragma unroll
        for (int mi = 0; mi < 4; ++mi)
            #pragma unroll
            for (int ni = 0; ni < 4; ++ni) {
                acc[mi][ni] = __builtin_amdgcn_mfma_f32_16x16x32_bf16(
                    af[1][mi], bfr[0][ni], acc[mi][ni], 0, 0, 0);   // lo*hi
                acc[mi][ni] = __builtin_amdgcn_mfma_f32_16x16x32_bf16(
                    af[0][mi], bfr[1][ni], acc[mi][ni], 0, 0, 0);   // hi*lo
                acc[mi][ni] = __builtin_amdgcn_mfma_f32_16x16x32_bf16(
                    af[0][mi], bfr[0][ni], acc[mi][ni], 0, 0, 0);   // hi*hi
            }
        __syncthreads();
        buf ^= 1;
    }

    // ---- epilogue ----
    #pragma unroll
    for (int mi = 0; mi < 4; ++mi) {
        #pragma unroll
        for (int r4 = 0; r4 < 4; ++r4) {
            int row = m0 + wm * 64 + mi * 16 + kfl * 4 + r4;
            if (MODE == 0) {
                int b = batch[row];
                #pragma unroll
                for (int ni = 0; ni < 4; ++ni) {
                    int col = n0 + wn * 64 + ni * 16 + rl;
                    float val = (acc[mi][ni][r4] + bias[col]) * kps[(size_t)b * CC + col];
                    Out[(size_t)row * CC + col] = val;
                }
            } else {
                #pragma unroll
                for (int ni = 0; ni < 4; ++ni) {
                    int col = n0 + wn * 64 + ni * 16 + rl;
                    Out[(size_t)row * CC + col] = acc[mi][ni][r4] + bias[col];
                }
            }
        }
    }
}

// ---------------------------------------------------------------------------
// K3a: per-(segment,chunk,channel) online max+sum partials
// ---------------------------------------------------------------------------
__global__ __launch_bounds__(256) void seg_stats_partial(
    const float* __restrict__ attn, const int* __restrict__ seg,
    float* __restrict__ pm, float* __restrict__ ps) {
    int b = blockIdx.x;
    int ch = blockIdx.y;
    int c = threadIdx.x;
    int s = seg[b], e = seg[b + 1];
    int len = e - s;
    int i0 = s + (int)((long long)len * ch / CH);
    int i1 = s + (int)((long long)len * (ch + 1) / CH);
    float m = -1e30f, sum = 0.f;
    for (int n = i0; n < i1; ++n) {
        float x = attn[(size_t)n * CC + c];
        float mn = fmaxf(m, x);
        sum = sum * __expf(m - mn) + __expf(x - mn);
        m = mn;
    }
    int idx = (b * CH + ch) * CC + c;
    pm[idx] = m;
    ps[idx] = sum;
}

// ---------------------------------------------------------------------------
// K3b: combine partials -> M[b,c], SV[b,c] = vp[b,c] / s[b,c]
// ---------------------------------------------------------------------------
__global__ __launch_bounds__(256) void seg_stats_combine(
    const float* __restrict__ pm, const float* __restrict__ ps,
    const float* __restrict__ vp,
    float* __restrict__ Mb, float* __restrict__ SVb) {
    int b = blockIdx.x;
    int c = threadIdx.x;
    float m = -1e30f;
    #pragma unroll
    for (int ch = 0; ch < CH; ++ch) m = fmaxf(m, pm[(b * CH + ch) * CC + c]);
    float s = 0.f;
    #pragma unroll
    for (int ch = 0; ch < CH; ++ch)
        s += ps[(b * CH + ch) * CC + c] * __expf(pm[(b * CH + ch) * CC + c] - m);
    Mb[b * CC + c] = m;
    SVb[b * CC + c] = vp[b * CC + c] / s;
}

// ---------------------------------------------------------------------------
extern "C" void kernel_launch(void* const* d_in, const int* in_sizes, int n_in,
                              void* d_out, int out_size, void* d_ws, size_t ws_size,
                              hipStream_t stream) {
    const float* q  = (const float*)d_in[0];
    const float* k  = (const float*)d_in[1];
    const float* v  = (const float*)d_in[2];
    const int* batch = (const int*)d_in[3];
    const float* Wq = (const float*)d_in[4];
    const float* bq = (const float*)d_in[5];
    const float* Wk = (const float*)d_in[6];
    const float* bk = (const float*)d_in[7];
    const float* Wv = (const float*)d_in[8];
    const float* bv = (const float*)d_in[9];
    const float* Wo = (const float*)d_in[10];
    const float* bo = (const float*)d_in[11];
    float* out = (float*)d_out;

    char* wsp = (char*)d_ws;
    float* attn = (float*)wsp;  wsp += (size_t)N_PTS * CC * sizeof(float);       // 134 MB
    float* kps  = (float*)wsp;  wsp += (size_t)BSEG * CC * sizeof(float);
    float* vp   = (float*)wsp;  wsp += (size_t)BSEG * CC * sizeof(float);
    float* Mb   = (float*)wsp;  wsp += (size_t)BSEG * CC * sizeof(float);
    float* SVb  = (float*)wsp;  wsp += (size_t)BSEG * CC * sizeof(float);
    float* pm   = (float*)wsp;  wsp += (size_t)BSEG * CH * CC * sizeof(float);
    float* ps   = (float*)wsp;  wsp += (size_t)BSEG * CH * CC * sizeof(float);
    short* W2q  = (short*)wsp;  wsp += (size_t)2 * 32 * 256 * 8 * sizeof(short); // 256 KB
    short* W2o  = (short*)wsp;  wsp += (size_t)2 * 32 * 256 * 8 * sizeof(short);
    int*   seg  = (int*)wsp;    wsp += (BSEG + 1) * sizeof(int);

    seg_bounds_kernel<<<1, 64, 0, stream>>>(batch, seg, N_PTS);
    kv_proj_kernel<<<BSEG, 256, 0, stream>>>(k, v, Wk, bk, Wv, bv, kps, vp);
    wsplit_kernel<<<64, 256, 0, stream>>>(Wq, Wo, W2q, W2o);

    gemm3_kernel<0><<<(N_PTS / BM) * (CC / BN), 256, 0, stream>>>(
        q, W2q, bq, attn, batch, kps, nullptr, nullptr);

    seg_stats_partial<<<dim3(BSEG, CH), 256, 0, stream>>>(attn, seg, pm, ps);
    seg_stats_combine<<<BSEG, 256, 0, stream>>>(pm, ps, vp, Mb, SVb);

    gemm3_kernel<1><<<(N_PTS / BM) * (CC / BN), 256, 0, stream>>>(
        attn, W2o, bo, out, batch, nullptr, Mb, SVb);
}

// Round 4
// 205.550 us; speedup vs baseline: 2.7014x; 1.2603x over previous
//
#include <hip/hip_runtime.h>
#include <math.h>

#define N_PTS 131072
#define BSEG 64
#define CC 256
#define BM 128
#define BK 32
#define NSTEP (CC / BK)          // 8 K-steps
#define LDS_SH 8192              // shorts per A buffer: 2 planes * 128 rows * 32 k
#define EXP_SHIFT 4.0f

#define INV_SQRT_DH 0.17677669529663687f  // 1/sqrt(32)

typedef short v8s __attribute__((ext_vector_type(8)));
typedef float v4f __attribute__((ext_vector_type(4)));

__device__ __forceinline__ float bf2f(unsigned short h) {
    unsigned u = ((unsigned)h) << 16;
    return __builtin_bit_cast(float, u);
}

// f32 -> bf16 round-to-nearest-even
__device__ __forceinline__ unsigned short f2bf(float f) {
    unsigned u = __builtin_bit_cast(unsigned, f);
    u += 0x7fffu + ((u >> 16) & 1u);
    return (unsigned short)(u >> 16);
}

// split 8 fp32 -> 8 bf16 hi + 8 bf16 lo (residual), packed as 4+4 ints
__device__ __forceinline__ void split8(const float* x, int* hi2, int* lo2) {
    #pragma unroll
    for (int i = 0; i < 4; ++i) {
        float a = x[2 * i], b = x[2 * i + 1];
        unsigned short ha = f2bf(a), hb = f2bf(b);
        float ra = a - bf2f(ha), rb = b - bf2f(hb);
        unsigned short la = f2bf(ra), lb = f2bf(rb);
        hi2[i] = (int)(((unsigned)hb << 16) | ha);
        lo2[i] = (int)(((unsigned)lb << 16) | la);
    }
}

__device__ __forceinline__ v8s as_v8s(int4 v) { return __builtin_bit_cast(v8s, v); }

// ---------------------------------------------------------------------------
// K1: kps = (k @ Wk^T + bk)/sqrt(DH) ; vp = v @ Wv^T + bv ; zero ssum
// ---------------------------------------------------------------------------
__global__ __launch_bounds__(256) void kv_proj_kernel(
    const float* __restrict__ k, const float* __restrict__ v,
    const float* __restrict__ Wk, const float* __restrict__ bk,
    const float* __restrict__ Wv, const float* __restrict__ bv,
    float* __restrict__ kps, float* __restrict__ vp, float* __restrict__ ssum) {
    int b = blockIdx.x;
    int c = threadIdx.x;
    const float4* krow  = (const float4*)(k + (size_t)b * CC);
    const float4* vrow  = (const float4*)(v + (size_t)b * CC);
    const float4* wkrow = (const float4*)(Wk + (size_t)c * CC);
    const float4* wvrow = (const float4*)(Wv + (size_t)c * CC);
    float accK = 0.f, accV = 0.f;
    #pragma unroll 8
    for (int i = 0; i < CC / 4; ++i) {
        float4 kk = krow[i], wk = wkrow[i];
        accK += kk.x * wk.x + kk.y * wk.y + kk.z * wk.z + kk.w * wk.w;
        float4 vv = vrow[i], wv = wvrow[i];
        accV += vv.x * wv.x + vv.y * wv.y + vv.z * wv.z + vv.w * wv.w;
    }
    kps[b * CC + c] = (accK + bk[c]) * INV_SQRT_DH;
    vp[b * CC + c] = accV + bv[c];
    ssum[b * CC + c] = 0.f;
}

// ---------------------------------------------------------------------------
// K1b: split Wq/Wo into hi/lo bf16 planes, layout W2[p][kf(32)][n(256)][8]
// ---------------------------------------------------------------------------
__global__ __launch_bounds__(256) void wsplit_kernel(
    const float* __restrict__ Wq, const float* __restrict__ Wo,
    short* __restrict__ W2q, short* __restrict__ W2o) {
    int bx = blockIdx.x;
    const float* W = (bx >= 32) ? Wo : Wq;
    short* W2 = (bx >= 32) ? W2o : W2q;
    int kf = bx & 31;
    int n = threadIdx.x;
    const float* src = W + (size_t)n * CC + kf * 8;
    float x[8];
    float4 x0 = *(const float4*)(src);
    float4 x1 = *(const float4*)(src + 4);
    x[0]=x0.x; x[1]=x0.y; x[2]=x0.z; x[3]=x0.w;
    x[4]=x1.x; x[5]=x1.y; x[6]=x1.z; x[7]=x1.w;
    int hi2[4], lo2[4];
    split8(x, hi2, lo2);
    *(int4*)&W2[((size_t)(0 * 32 + kf) * 256 + n) * 8] = make_int4(hi2[0], hi2[1], hi2[2], hi2[3]);
    *(int4*)&W2[((size_t)(1 * 32 + kf) * 256 + n) * 8] = make_int4(lo2[0], lo2[1], lo2[2], lo2[3]);
}

// ---------------------------------------------------------------------------
// GEMM (bf16x3 MFMA), BM=128 x BN=256(full), 512 thr / 8 waves.
//  A staged (fp32 -> split bf16) in LDS dbuf; B frags straight from global (L2).
//  MODE 0: A=q. Epilogue: p = exp((acc+bq[c])*kps[b,c] - 4) -> attn;
//          fused segment-sum: atomicAdd ssum[b,c] += p.
//  MODE 1: A=p with stage x = p * SV[b,c].  Epilogue: acc + bo[c] -> out.
// ---------------------------------------------------------------------------
template <int MODE>
__global__ __launch_bounds__(512, 4) void gemm3_kernel(
    const float* __restrict__ A, const short* __restrict__ W2,
    const float* __restrict__ bias, float* __restrict__ Out,
    const int* __restrict__ batch, const float* __restrict__ kps,
    const float* __restrict__ SV, float* __restrict__ ssum) {
    __shared__ short lds[2 * LDS_SH];   // 32 KB

    const int tid = threadIdx.x;
    const int lane = tid & 63;
    const int w = tid >> 6;
    const int wm = w >> 2, wn = w & 3;        // 2 x 4 waves, 64x64 tiles
    const int kfl = lane >> 4;                // k-chunk 0..3
    const int rl = lane & 15;                 // row/col within frag
    const int m0 = blockIdx.x * BM;

    v4f acc[4][4];
    #pragma unroll
    for (int i = 0; i < 4; ++i)
        #pragma unroll
        for (int j = 0; j < 4; ++j) acc[i][j] = (v4f){0.f, 0.f, 0.f, 0.f};

    auto stageA = [&](int buf, int s) {
        int m = tid >> 2, kf = tid & 3;       // one float8 item per thread
        const float* src = A + (size_t)(m0 + m) * CC + s * BK + kf * 8;
        float4 x0 = *(const float4*)(src);
        float4 x1 = *(const float4*)(src + 4);
        float x[8];
        x[0]=x0.x; x[1]=x0.y; x[2]=x0.z; x[3]=x0.w;
        x[4]=x1.x; x[5]=x1.y; x[6]=x1.z; x[7]=x1.w;
        if (MODE == 1) {
            int b = batch[m0 + m];
            const float* sp = SV + (size_t)b * CC + s * BK + kf * 8;
            float4 s0v = *(const float4*)(sp);
            float4 s1v = *(const float4*)(sp + 4);
            x[0] *= s0v.x; x[1] *= s0v.y; x[2] *= s0v.z; x[3] *= s0v.w;
            x[4] *= s1v.x; x[5] *= s1v.y; x[6] *= s1v.z; x[7] *= s1v.w;
        }
        int hi2[4], lo2[4];
        split8(x, hi2, lo2);
        int slot = kf * 128 + m;
        *(int4*)&lds[buf * LDS_SH + (size_t)slot * 8] =
            make_int4(hi2[0], hi2[1], hi2[2], hi2[3]);
        *(int4*)&lds[buf * LDS_SH + (size_t)(512 + slot) * 8] =
            make_int4(lo2[0], lo2[1], lo2[2], lo2[3]);
    };

    stageA(0, 0);
    __syncthreads();

    int buf = 0;
    for (int s = 0; s < NSTEP; ++s) {
        // B fragments for this K-step: straight from global (L2-resident, 256KB)
        v8s bfr[2][4];
        #pragma unroll
        for (int p = 0; p < 2; ++p)
            #pragma unroll
            for (int ni = 0; ni < 4; ++ni)
                bfr[p][ni] = as_v8s(*(const int4*)(W2 +
                    ((size_t)(p * 32 + s * 4 + kfl) * 256 + wn * 64 + ni * 16 + rl) * 8));

        if (s + 1 < NSTEP) stageA(buf ^ 1, s + 1);

        #pragma unroll
        for (int mi = 0; mi < 4; ++mi) {
            v8s a0 = as_v8s(*(const int4*)&lds[buf * LDS_SH +
                (size_t)(kfl * 128 + wm * 64 + mi * 16 + rl) * 8]);
            v8s a1 = as_v8s(*(const int4*)&lds[buf * LDS_SH +
                (size_t)(512 + kfl * 128 + wm * 64 + mi * 16 + rl) * 8]);
            #pragma unroll
            for (int ni = 0; ni < 4; ++ni) {
                acc[mi][ni] = __builtin_amdgcn_mfma_f32_16x16x32_bf16(
                    a1, bfr[0][ni], acc[mi][ni], 0, 0, 0);   // lo*hi
                acc[mi][ni] = __builtin_amdgcn_mfma_f32_16x16x32_bf16(
                    a0, bfr[1][ni], acc[mi][ni], 0, 0, 0);   // hi*lo
                acc[mi][ni] = __builtin_amdgcn_mfma_f32_16x16x32_bf16(
                    a0, bfr[0][ni], acc[mi][ni], 0, 0, 0);   // hi*hi
            }
        }
        __syncthreads();
        buf ^= 1;
    }

    const int colb = wn * 64 + rl;

    if (MODE == 0) {
        int bfirst = batch[m0];
        int blast = batch[m0 + BM - 1];
        if (bfirst == blast) {
            // fast path: whole block in one segment
            int b = bfirst;
            float bb[4], kk[4], csum[4];
            #pragma unroll
            for (int ni = 0; ni < 4; ++ni) {
                int col = colb + ni * 16;
                bb[ni] = bias[col];
                kk[ni] = kps[(size_t)b * CC + col];
                csum[ni] = 0.f;
            }
            #pragma unroll
            for (int mi = 0; mi < 4; ++mi)
                #pragma unroll
                for (int r4 = 0; r4 < 4; ++r4) {
                    int row = m0 + wm * 64 + mi * 16 + kfl * 4 + r4;
                    #pragma unroll
                    for (int ni = 0; ni < 4; ++ni) {
                        float p = __expf((acc[mi][ni][r4] + bb[ni]) * kk[ni] - EXP_SHIFT);
                        Out[(size_t)row * CC + colb + ni * 16] = p;
                        csum[ni] += p;
                    }
                }
            #pragma unroll
            for (int ni = 0; ni < 4; ++ni) {
                float vsum = csum[ni];
                vsum += __shfl_xor(vsum, 16);
                vsum += __shfl_xor(vsum, 32);
                if (kfl == 0) atomicAdd(&ssum[(size_t)b * CC + colb + ni * 16], vsum);
            }
        } else {
            // slow path: segment boundary inside block (rare)
            int curb = -1;
            float racc[4] = {0.f, 0.f, 0.f, 0.f};
            #pragma unroll
            for (int mi = 0; mi < 4; ++mi)
                #pragma unroll
                for (int r4 = 0; r4 < 4; ++r4) {
                    int row = m0 + wm * 64 + mi * 16 + kfl * 4 + r4;
                    int b = batch[row];
                    if (b != curb) {
                        if (curb >= 0) {
                            #pragma unroll
                            for (int ni = 0; ni < 4; ++ni) {
                                atomicAdd(&ssum[(size_t)curb * CC + colb + ni * 16], racc[ni]);
                                racc[ni] = 0.f;
                            }
                        }
                        curb = b;
                    }
                    #pragma unroll
                    for (int ni = 0; ni < 4; ++ni) {
                        int col = colb + ni * 16;
                        float p = __expf((acc[mi][ni][r4] + bias[col]) *
                                         kps[(size_t)b * CC + col] - EXP_SHIFT);
                        Out[(size_t)row * CC + col] = p;
                        racc[ni] += p;
                    }
                }
            #pragma unroll
            for (int ni = 0; ni < 4; ++ni)
                atomicAdd(&ssum[(size_t)curb * CC + colb + ni * 16], racc[ni]);
        }
    } else {
        #pragma unroll
        for (int mi = 0; mi < 4; ++mi)
            #pragma unroll
            for (int r4 = 0; r4 < 4; ++r4) {
                int row = m0 + wm * 64 + mi * 16 + kfl * 4 + r4;
                #pragma unroll
                for (int ni = 0; ni < 4; ++ni) {
                    int col = colb + ni * 16;
                    Out[(size_t)row * CC + col] = acc[mi][ni][r4] + bias[col];
                }
            }
    }
}

// ---------------------------------------------------------------------------
// K_sv: SV[b,c] = vp[b,c] / ssum[b,c]  (inf only for empty segments: never read)
// ---------------------------------------------------------------------------
__global__ __launch_bounds__(256) void sv_kernel(
    const float* __restrict__ vp, const float* __restrict__ ssum,
    float* __restrict__ SV) {
    int i = blockIdx.x * 256 + threadIdx.x;
    SV[i] = vp[i] / ssum[i];
}

// ---------------------------------------------------------------------------
extern "C" void kernel_launch(void* const* d_in, const int* in_sizes, int n_in,
                              void* d_out, int out_size, void* d_ws, size_t ws_size,
                              hipStream_t stream) {
    const float* q  = (const float*)d_in[0];
    const float* k  = (const float*)d_in[1];
    const float* v  = (const float*)d_in[2];
    const int* batch = (const int*)d_in[3];
    const float* Wq = (const float*)d_in[4];
    const float* bq = (const float*)d_in[5];
    const float* Wk = (const float*)d_in[6];
    const float* bk = (const float*)d_in[7];
    const float* Wv = (const float*)d_in[8];
    const float* bv = (const float*)d_in[9];
    const float* Wo = (const float*)d_in[10];
    const float* bo = (const float*)d_in[11];
    float* out = (float*)d_out;

    char* wsp = (char*)d_ws;
    float* attn = (float*)wsp;  wsp += (size_t)N_PTS * CC * sizeof(float);       // 134 MB
    float* kps  = (float*)wsp;  wsp += (size_t)BSEG * CC * sizeof(float);
    float* vp   = (float*)wsp;  wsp += (size_t)BSEG * CC * sizeof(float);
    float* SVb  = (float*)wsp;  wsp += (size_t)BSEG * CC * sizeof(float);
    float* ssum = (float*)wsp;  wsp += (size_t)BSEG * CC * sizeof(float);
    short* W2q  = (short*)wsp;  wsp += (size_t)2 * 32 * 256 * 8 * sizeof(short); // 256 KB
    short* W2o  = (short*)wsp;  wsp += (size_t)2 * 32 * 256 * 8 * sizeof(short);

    kv_proj_kernel<<<BSEG, 256, 0, stream>>>(k, v, Wk, bk, Wv, bv, kps, vp, ssum);
    wsplit_kernel<<<64, 256, 0, stream>>>(Wq, Wo, W2q, W2o);

    gemm3_kernel<0><<<N_PTS / BM, 512, 0, stream>>>(
        q, W2q, bq, attn, batch, kps, nullptr, ssum);

    sv_kernel<<<BSEG, 256, 0, stream>>>(vp, ssum, SVb);

    gemm3_kernel<1><<<N_PTS / BM, 512, 0, stream>>>(
        attn, W2o, bo, out, batch, nullptr, SVb, nullptr);
}